// Round 4
// baseline (832.316 us; speedup 1.0000x reference)
//
#include <hip/hip_runtime.h>

typedef __attribute__((ext_vector_type(8))) short bf16x8;
typedef __attribute__((ext_vector_type(4))) float f32x4;
typedef unsigned short u16;
typedef unsigned int u32;

constexpr int kH   = 2048;   // hidden
constexpr int kI   = 1024;   // intermediate
constexpr int kE   = 32;     // experts
constexpr int kK   = 8;      // experts per token
constexpr int kG   = 8;      // groups
constexpr int kKG  = 4;      // groups kept
constexpr int kCap = 1024;   // capacity
constexpr float kScale = 2.5f;

__device__ __forceinline__ u16 f2bf(float f) {
    union { float f; u32 u; } v; v.f = f;
    u32 u = v.u + 0x7FFFu + ((v.u >> 16) & 1u);  // RNE
    return (u16)(u >> 16);
}
__device__ __forceinline__ u32 pk2(float a, float b) {
    return (u32)f2bf(a) | ((u32)f2bf(b) << 16);
}
// XOR-swizzled element index for a [row][64] bf16 LDS tile (128 B rows).
__device__ __forceinline__ int swz(int row, int k) {
    return row * 64 + (k ^ ((((row >> 3) ^ row) & 7) << 3));
}

// ---------------- gate: sigmoid scores + group-limited top-k routing ----------------
__global__ __launch_bounds__(256) void gate_kernel(
    const float* __restrict__ x, const float* __restrict__ w_gate,
    const float* __restrict__ gbias,
    int* __restrict__ cnt, int* __restrict__ tok_of_slot, float* __restrict__ wt_of_slot)
{
    int tok = blockIdx.x;
    int t = threadIdx.x;
    __shared__ float part[256];
    __shared__ float sc[kE], sb[kE];

    const float* xr = x + (size_t)tok * kH;
    int e = t & 31, c = t >> 5;
    const float* wg = w_gate + e;
    float s = 0.f;
    #pragma unroll 4
    for (int h = c * 256; h < c * 256 + 256; ++h)
        s += xr[h] * wg[(size_t)h * kE];
    part[t] = s;
    __syncthreads();

    if (t < kE) {
        float logit = 0.f;
        #pragma unroll
        for (int cc = 0; cc < 8; ++cc) logit += part[t + 32 * cc];
        float sco = 1.f / (1.f + expf(-logit));
        sc[t] = sco;
        sb[t] = sco + gbias[t];
    }
    __syncthreads();

    if (t == 0) {
        float gsc[kG];
        for (int g = 0; g < kG; ++g) {
            float m1 = -1e30f, m2 = -1e30f;
            for (int j = 0; j < 4; ++j) {
                float v = sb[g * 4 + j];
                if (v > m1) { m2 = m1; m1 = v; } else if (v > m2) { m2 = v; }
            }
            gsc[g] = m1 + m2;
        }
        bool gkeep[kG];
        for (int g = 0; g < kG; ++g) gkeep[g] = false;
        for (int it = 0; it < kKG; ++it) {
            float best = -1e30f; int bi = 0;
            for (int g = 0; g < kG; ++g)
                if (!gkeep[g] && gsc[g] > best) { best = gsc[g]; bi = g; }
            gkeep[bi] = true;
        }
        bool taken[kE];
        for (int i = 0; i < kE; ++i) taken[i] = false;
        int sel[kK]; float selw[kK]; float wsum = 0.f;
        for (int it = 0; it < kK; ++it) {
            float best = -1e30f; int bi = 0;
            for (int i = 0; i < kE; ++i)
                if (gkeep[i >> 2] && !taken[i] && sb[i] > best) { best = sb[i]; bi = i; }
            taken[bi] = true;
            sel[it] = bi; selw[it] = sc[bi]; wsum += sc[bi];
        }
        float scl = kScale / wsum;
        for (int it = 0; it < kK; ++it) {
            int ee = sel[it];
            int slot = atomicAdd(&cnt[ee], 1);
            if (slot < kCap) {
                tok_of_slot[ee * kCap + slot] = tok;
                wt_of_slot[ee * kCap + slot] = selw[it] * scl;
            }
        }
    }
}

// ---------------- prep_x: fp32 -> bf16 streaming convert ----------------
__global__ __launch_bounds__(256) void prep_x_kernel(
    const float* __restrict__ src, u16* __restrict__ dst, int n8)
{
    int i = blockIdx.x * 256 + threadIdx.x;
    if (i >= n8) return;
    const float* p = src + (size_t)i * 8;
    float4 a = *(const float4*)p;
    float4 b = *(const float4*)(p + 4);
    uint4 o;
    o.x = pk2(a.x, a.y); o.y = pk2(a.z, a.w);
    o.z = pk2(b.x, b.y); o.w = pk2(b.z, b.w);
    *(uint4*)(dst + (size_t)i * 8) = o;
}

// ---------------- prep_w: per-expert [R][C] fp32 -> [C][R] bf16 transpose ----------------
__global__ __launch_bounds__(256) void prep_w_kernel(
    const float* __restrict__ src, u16* __restrict__ dst, int R, int C)
{
    __shared__ u16 Tl[64 * 64];
    int e = blockIdx.z;
    int n0 = blockIdx.x * 64;   // C-dim (output row)
    int k0 = blockIdx.y * 64;   // R-dim (output col)
    int t = threadIdx.x;

    const float* se = src + (size_t)e * R * C;
    u16* de = dst + (size_t)e * R * C;

    // phase 1: 4x4 register transpose into swizzled LDS [n][k]
    {
        int bn = (t & 15) * 4, bk = (t >> 4) * 4;
        const float* p = se + (size_t)(k0 + bk) * C + n0 + bn;
        float4 c0 = *(const float4*)p;
        float4 c1 = *(const float4*)(p + C);
        float4 c2 = *(const float4*)(p + 2 * C);
        float4 c3 = *(const float4*)(p + 3 * C);
        uint2 q;
        q.x = pk2(c0.x, c1.x); q.y = pk2(c2.x, c3.x); *(uint2*)&Tl[swz(bn + 0, bk)] = q;
        q.x = pk2(c0.y, c1.y); q.y = pk2(c2.y, c3.y); *(uint2*)&Tl[swz(bn + 1, bk)] = q;
        q.x = pk2(c0.z, c1.z); q.y = pk2(c2.z, c3.z); *(uint2*)&Tl[swz(bn + 2, bk)] = q;
        q.x = pk2(c0.w, c1.w); q.y = pk2(c2.w, c3.w); *(uint2*)&Tl[swz(bn + 3, bk)] = q;
    }
    __syncthreads();
    // phase 2: b128 swizzled read, coalesced global write
    #pragma unroll
    for (int r = 0; r < 2; ++r) {
        int f = r * 256 + t;
        int n = f >> 3, kk = (f & 7) * 8;
        uint4 v = *(const uint4*)&Tl[swz(n, kk)];
        *(uint4*)(de + (size_t)(n0 + n) * R + k0 + kk) = v;
    }
}

// ---------------- GEMM1 (bf16 inputs): act = silu(xb@w1t^T)*(xb@w3t^T) ----------------
__global__ __launch_bounds__(256, 3) void gemm1_kernel(
    const u16* __restrict__ xb, const u16* __restrict__ w1t, const u16* __restrict__ w3t,
    const int* __restrict__ tok_of_slot, const int* __restrict__ cnt,
    u16* __restrict__ act)
{
    int e = blockIdx.z;
    int count = cnt[e];
    int m0 = blockIdx.y * 128;
    if (m0 >= count) return;
    int n0 = blockIdx.x * 64;

    __shared__ u16 As[128 * 64];
    __shared__ u16 B1s[64 * 64];
    __shared__ u16 B3s[64 * 64];
    __shared__ int toks[128];

    int t = threadIdx.x;
    if (t < 128) {
        int s = m0 + t;
        toks[t] = (s < count) ? tok_of_slot[e * kCap + s] : -1;
    }

    int lane = t & 63;
    int wv = t >> 6;
    int wm = (wv >> 1) * 64;
    int wn = (wv & 1) * 32;
    int lr = lane & 15;
    int kg = lane >> 4;

    f32x4 accg[4][2], accu[4][2];
    #pragma unroll
    for (int i = 0; i < 4; ++i)
        #pragma unroll
        for (int j = 0; j < 2; ++j) {
            accg[i][j] = f32x4{0.f, 0.f, 0.f, 0.f};
            accu[i][j] = f32x4{0.f, 0.f, 0.f, 0.f};
        }

    const u16* w1e = w1t + (size_t)e * kH * kI;
    const u16* w3e = w3t + (size_t)e * kH * kI;

    for (int k0 = 0; k0 < kH; k0 += 64) {
        __syncthreads();
        // stage A: gathered bf16 x rows, pure b128 copy
        #pragma unroll
        for (int r = 0; r < 4; ++r) {
            int f = r * 256 + t;
            int row = f >> 3, kk = (f & 7) * 8;
            int tk = toks[row];
            uint4 v = make_uint4(0, 0, 0, 0);
            if (tk >= 0) v = *(const uint4*)(xb + (size_t)tk * kH + k0 + kk);
            *(uint4*)&As[swz(row, kk)] = v;
        }
        // stage B1/B3: [n][k] bf16 rows, pure b128 copy
        #pragma unroll
        for (int r = 0; r < 2; ++r) {
            int f = r * 256 + t;
            int n = f >> 3, kk = (f & 7) * 8;
            uint4 v1 = *(const uint4*)(w1e + (size_t)(n0 + n) * kH + k0 + kk);
            *(uint4*)&B1s[swz(n, kk)] = v1;
            uint4 v3 = *(const uint4*)(w3e + (size_t)(n0 + n) * kH + k0 + kk);
            *(uint4*)&B3s[swz(n, kk)] = v3;
        }
        __syncthreads();
        #pragma unroll
        for (int h = 0; h < 2; ++h) {
            int kk = h * 32 + kg * 8;
            bf16x8 a[4];
            #pragma unroll
            for (int i = 0; i < 4; ++i)
                a[i] = *(const bf16x8*)&As[swz(wm + i * 16 + lr, kk)];
            #pragma unroll
            for (int ni = 0; ni < 2; ++ni) {
                bf16x8 b1 = *(const bf16x8*)&B1s[swz(wn + ni * 16 + lr, kk)];
                bf16x8 b3 = *(const bf16x8*)&B3s[swz(wn + ni * 16 + lr, kk)];
                #pragma unroll
                for (int mi = 0; mi < 4; ++mi) {
                    accg[mi][ni] = __builtin_amdgcn_mfma_f32_16x16x32_bf16(a[mi], b1, accg[mi][ni], 0, 0, 0);
                    accu[mi][ni] = __builtin_amdgcn_mfma_f32_16x16x32_bf16(a[mi], b3, accu[mi][ni], 0, 0, 0);
                }
            }
        }
    }

    u16* actp = act + (size_t)e * kCap * kI;
    #pragma unroll
    for (int mi = 0; mi < 4; ++mi)
        #pragma unroll
        for (int ni = 0; ni < 2; ++ni)
            #pragma unroll
            for (int j = 0; j < 4; ++j) {
                int srow = m0 + wm + mi * 16 + kg * 4 + j;
                int icol = n0 + wn + ni * 16 + lr;
                float g = accg[mi][ni][j], u = accu[mi][ni][j];
                float sg = g / (1.f + __expf(-g));
                actp[(size_t)srow * kI + icol] = f2bf(sg * u);
            }
}

// ---------------- GEMM2 (bf16 inputs): y = act @ w2t^T; out[tok] += w*y ----------------
__global__ __launch_bounds__(256, 3) void gemm2_kernel(
    const u16* __restrict__ act, const u16* __restrict__ w2t,
    const int* __restrict__ tok_of_slot, const float* __restrict__ wt_of_slot,
    const int* __restrict__ cnt, float* __restrict__ out)
{
    int e = blockIdx.z;
    int count = cnt[e];
    int m0 = blockIdx.y * 128;
    if (m0 >= count) return;
    int n0 = blockIdx.x * 128;

    __shared__ u16 As[128 * 64];
    __shared__ u16 Bs[128 * 64];
    __shared__ int toks[128];
    __shared__ float wts[128];

    int t = threadIdx.x;
    if (t < 128) {
        int s = m0 + t;
        toks[t] = (s < count) ? tok_of_slot[e * kCap + s] : 0;
        wts[t]  = (s < count) ? wt_of_slot[e * kCap + s] : 0.f;
    }

    int lane = t & 63;
    int wv = t >> 6;
    int wm = (wv >> 1) * 64;
    int wn = (wv & 1) * 64;
    int lr = lane & 15;
    int kg = lane >> 4;

    f32x4 acc[4][4];
    #pragma unroll
    for (int i = 0; i < 4; ++i)
        #pragma unroll
        for (int j = 0; j < 4; ++j) acc[i][j] = f32x4{0.f, 0.f, 0.f, 0.f};

    const u16* ae = act + (size_t)e * kCap * kI;
    const u16* w2e = w2t + (size_t)e * kI * kH;

    for (int k0 = 0; k0 < kI; k0 += 64) {
        __syncthreads();
        #pragma unroll
        for (int r = 0; r < 4; ++r) {
            int f = r * 256 + t;
            int row = f >> 3, kk = (f & 7) * 8;
            uint4 v = *(const uint4*)(ae + (size_t)(m0 + row) * kI + k0 + kk);
            *(uint4*)&As[swz(row, kk)] = v;
        }
        #pragma unroll
        for (int r = 0; r < 4; ++r) {
            int f = r * 256 + t;
            int n = f >> 3, kk = (f & 7) * 8;
            uint4 v = *(const uint4*)(w2e + (size_t)(n0 + n) * kI + k0 + kk);
            *(uint4*)&Bs[swz(n, kk)] = v;
        }
        __syncthreads();
        #pragma unroll
        for (int h = 0; h < 2; ++h) {
            int kk = h * 32 + kg * 8;
            bf16x8 a[4];
            #pragma unroll
            for (int i = 0; i < 4; ++i)
                a[i] = *(const bf16x8*)&As[swz(wm + i * 16 + lr, kk)];
            #pragma unroll
            for (int ni = 0; ni < 4; ++ni) {
                bf16x8 b = *(const bf16x8*)&Bs[swz(wn + ni * 16 + lr, kk)];
                #pragma unroll
                for (int mi = 0; mi < 4; ++mi)
                    acc[mi][ni] = __builtin_amdgcn_mfma_f32_16x16x32_bf16(a[mi], b, acc[mi][ni], 0, 0, 0);
            }
        }
    }

    #pragma unroll
    for (int mi = 0; mi < 4; ++mi)
        #pragma unroll
        for (int ni = 0; ni < 4; ++ni)
            #pragma unroll
            for (int j = 0; j < 4; ++j) {
                int sr = wm + mi * 16 + kg * 4 + j;
                if (m0 + sr < count) {
                    atomicAdd(&out[(size_t)toks[sr] * kH + n0 + wn + ni * 16 + lr],
                              wts[sr] * acc[mi][ni][j]);
                }
            }
}

// ================= legacy fp32-staging kernels (fallback if ws too small) =================
__global__ __launch_bounds__(256, 3) void gemm1_legacy(
    const float* __restrict__ x, const float* __restrict__ w1g, const float* __restrict__ w3g,
    const int* __restrict__ tok_of_slot, const int* __restrict__ cnt,
    u16* __restrict__ act)
{
    int e = blockIdx.z;
    int count = cnt[e];
    int m0 = blockIdx.y * 128;
    if (m0 >= count) return;
    int n0 = blockIdx.x * 64;

    __shared__ u16 As[128 * 64];
    __shared__ u16 B1s[64 * 64];
    __shared__ u16 B3s[64 * 64];
    __shared__ int toks[128];

    int t = threadIdx.x;
    if (t < 128) {
        int s = m0 + t;
        toks[t] = (s < count) ? tok_of_slot[e * kCap + s] : -1;
    }
    int lane = t & 63, wv = t >> 6;
    int wm = (wv >> 1) * 64, wn = (wv & 1) * 32;
    int lr = lane & 15, kg = lane >> 4;

    f32x4 accg[4][2], accu[4][2];
    #pragma unroll
    for (int i = 0; i < 4; ++i)
        #pragma unroll
        for (int j = 0; j < 2; ++j) {
            accg[i][j] = f32x4{0.f, 0.f, 0.f, 0.f};
            accu[i][j] = f32x4{0.f, 0.f, 0.f, 0.f};
        }
    const float* w1e = w1g + (size_t)e * kH * kI;
    const float* w3e = w3g + (size_t)e * kH * kI;

    for (int k0 = 0; k0 < kH; k0 += 64) {
        __syncthreads();
        #pragma unroll
        for (int r = 0; r < 4; ++r) {
            int f = r * 256 + t;
            int row = f >> 3, k8 = (f & 7) * 8;
            int tk = toks[row];
            float4 v0 = make_float4(0.f, 0.f, 0.f, 0.f), v1 = v0;
            if (tk >= 0) {
                const float* p = x + (size_t)tk * kH + k0 + k8;
                v0 = *(const float4*)p; v1 = *(const float4*)(p + 4);
            }
            uint4 w;
            w.x = pk2(v0.x, v0.y); w.y = pk2(v0.z, v0.w);
            w.z = pk2(v1.x, v1.y); w.w = pk2(v1.z, v1.w);
            *(uint4*)&As[swz(row, k8)] = w;
        }
        {
            int bn = (t & 15) * 4, bk = (t >> 4) * 4;
            const float* p1 = w1e + (size_t)(k0 + bk) * kI + n0 + bn;
            float4 c0 = *(const float4*)p1, c1 = *(const float4*)(p1 + kI),
                   c2 = *(const float4*)(p1 + 2 * kI), c3 = *(const float4*)(p1 + 3 * kI);
            uint2 q;
            q.x = pk2(c0.x, c1.x); q.y = pk2(c2.x, c3.x); *(uint2*)&B1s[swz(bn + 0, bk)] = q;
            q.x = pk2(c0.y, c1.y); q.y = pk2(c2.y, c3.y); *(uint2*)&B1s[swz(bn + 1, bk)] = q;
            q.x = pk2(c0.z, c1.z); q.y = pk2(c2.z, c3.z); *(uint2*)&B1s[swz(bn + 2, bk)] = q;
            q.x = pk2(c0.w, c1.w); q.y = pk2(c2.w, c3.w); *(uint2*)&B1s[swz(bn + 3, bk)] = q;
            const float* p3 = w3e + (size_t)(k0 + bk) * kI + n0 + bn;
            c0 = *(const float4*)p3; c1 = *(const float4*)(p3 + kI);
            c2 = *(const float4*)(p3 + 2 * kI); c3 = *(const float4*)(p3 + 3 * kI);
            q.x = pk2(c0.x, c1.x); q.y = pk2(c2.x, c3.x); *(uint2*)&B3s[swz(bn + 0, bk)] = q;
            q.x = pk2(c0.y, c1.y); q.y = pk2(c2.y, c3.y); *(uint2*)&B3s[swz(bn + 1, bk)] = q;
            q.x = pk2(c0.z, c1.z); q.y = pk2(c2.z, c3.z); *(uint2*)&B3s[swz(bn + 2, bk)] = q;
            q.x = pk2(c0.w, c1.w); q.y = pk2(c2.w, c3.w); *(uint2*)&B3s[swz(bn + 3, bk)] = q;
        }
        __syncthreads();
        #pragma unroll
        for (int h = 0; h < 2; ++h) {
            int kk = h * 32 + kg * 8;
            bf16x8 a[4];
            #pragma unroll
            for (int i = 0; i < 4; ++i)
                a[i] = *(const bf16x8*)&As[swz(wm + i * 16 + lr, kk)];
            #pragma unroll
            for (int ni = 0; ni < 2; ++ni) {
                bf16x8 b1 = *(const bf16x8*)&B1s[swz(wn + ni * 16 + lr, kk)];
                bf16x8 b3 = *(const bf16x8*)&B3s[swz(wn + ni * 16 + lr, kk)];
                #pragma unroll
                for (int mi = 0; mi < 4; ++mi) {
                    accg[mi][ni] = __builtin_amdgcn_mfma_f32_16x16x32_bf16(a[mi], b1, accg[mi][ni], 0, 0, 0);
                    accu[mi][ni] = __builtin_amdgcn_mfma_f32_16x16x32_bf16(a[mi], b3, accu[mi][ni], 0, 0, 0);
                }
            }
        }
    }
    u16* actp = act + (size_t)e * kCap * kI;
    #pragma unroll
    for (int mi = 0; mi < 4; ++mi)
        #pragma unroll
        for (int ni = 0; ni < 2; ++ni)
            #pragma unroll
            for (int j = 0; j < 4; ++j) {
                int srow = m0 + wm + mi * 16 + kg * 4 + j;
                int icol = n0 + wn + ni * 16 + lr;
                float g = accg[mi][ni][j], u = accu[mi][ni][j];
                float sg = g / (1.f + __expf(-g));
                actp[(size_t)srow * kI + icol] = f2bf(sg * u);
            }
}

__global__ __launch_bounds__(256, 3) void gemm2_legacy(
    const u16* __restrict__ act, const float* __restrict__ w2g,
    const int* __restrict__ tok_of_slot, const float* __restrict__ wt_of_slot,
    const int* __restrict__ cnt, float* __restrict__ out)
{
    int e = blockIdx.z;
    int count = cnt[e];
    int m0 = blockIdx.y * 128;
    if (m0 >= count) return;
    int n0 = blockIdx.x * 128;

    __shared__ u16 As[128 * 64];
    __shared__ u16 Bs[128 * 64];
    __shared__ int toks[128];
    __shared__ float wts[128];

    int t = threadIdx.x;
    if (t < 128) {
        int s = m0 + t;
        toks[t] = (s < count) ? tok_of_slot[e * kCap + s] : 0;
        wts[t]  = (s < count) ? wt_of_slot[e * kCap + s] : 0.f;
    }
    int lane = t & 63, wv = t >> 6;
    int wm = (wv >> 1) * 64, wn = (wv & 1) * 64;
    int lr = lane & 15, kg = lane >> 4;

    f32x4 acc[4][4];
    #pragma unroll
    for (int i = 0; i < 4; ++i)
        #pragma unroll
        for (int j = 0; j < 4; ++j) acc[i][j] = f32x4{0.f, 0.f, 0.f, 0.f};

    const u16* ae = act + (size_t)e * kCap * kI;
    const float* w2e = w2g + (size_t)e * kI * kH;

    for (int k0 = 0; k0 < kI; k0 += 64) {
        __syncthreads();
        #pragma unroll
        for (int r = 0; r < 4; ++r) {
            int f = r * 256 + t;
            int row = f >> 3, k8 = (f & 7) * 8;
            uint4 v = *(const uint4*)(ae + (size_t)(m0 + row) * kI + k0 + k8);
            *(uint4*)&As[swz(row, k8)] = v;
        }
        #pragma unroll
        for (int r = 0; r < 2; ++r) {
            int f = r * 256 + t;
            int bn = (f & 31) * 4, bk = (f >> 5) * 4;
            const float* p = w2e + (size_t)(k0 + bk) * kH + n0 + bn;
            float4 c0 = *(const float4*)p, c1 = *(const float4*)(p + kH),
                   c2 = *(const float4*)(p + 2 * kH), c3 = *(const float4*)(p + 3 * kH);
            uint2 q;
            q.x = pk2(c0.x, c1.x); q.y = pk2(c2.x, c3.x); *(uint2*)&Bs[swz(bn + 0, bk)] = q;
            q.x = pk2(c0.y, c1.y); q.y = pk2(c2.y, c3.y); *(uint2*)&Bs[swz(bn + 1, bk)] = q;
            q.x = pk2(c0.z, c1.z); q.y = pk2(c2.z, c3.z); *(uint2*)&Bs[swz(bn + 2, bk)] = q;
            q.x = pk2(c0.w, c1.w); q.y = pk2(c2.w, c3.w); *(uint2*)&Bs[swz(bn + 3, bk)] = q;
        }
        __syncthreads();
        #pragma unroll
        for (int h = 0; h < 2; ++h) {
            int kk = h * 32 + kg * 8;
            bf16x8 a[4];
            #pragma unroll
            for (int i = 0; i < 4; ++i)
                a[i] = *(const bf16x8*)&As[swz(wm + i * 16 + lr, kk)];
            #pragma unroll
            for (int ni = 0; ni < 4; ++ni) {
                bf16x8 b = *(const bf16x8*)&Bs[swz(wn + ni * 16 + lr, kk)];
                #pragma unroll
                for (int mi = 0; mi < 4; ++mi)
                    acc[mi][ni] = __builtin_amdgcn_mfma_f32_16x16x32_bf16(a[mi], b, acc[mi][ni], 0, 0, 0);
            }
        }
    }
    #pragma unroll
    for (int mi = 0; mi < 4; ++mi)
        #pragma unroll
        for (int ni = 0; ni < 4; ++ni)
            #pragma unroll
            for (int j = 0; j < 4; ++j) {
                int sr = wm + mi * 16 + kg * 4 + j;
                if (m0 + sr < count) {
                    atomicAdd(&out[(size_t)toks[sr] * kH + n0 + wn + ni * 16 + lr],
                              wts[sr] * acc[mi][ni][j]);
                }
            }
}

extern "C" void kernel_launch(void* const* d_in, const int* in_sizes, int n_in,
                              void* d_out, int out_size, void* d_ws, size_t ws_size,
                              hipStream_t stream) {
    const float* x      = (const float*)d_in[0];
    const float* w_gate = (const float*)d_in[1];
    const float* gbias  = (const float*)d_in[2];
    const float* w1     = (const float*)d_in[3];
    const float* w3     = (const float*)d_in[4];
    const float* w2     = (const float*)d_in[5];
    float* out = (float*)d_out;

    int ntok = in_sizes[0] / kH;

    char* ws = (char*)d_ws;
    size_t off = 0;
    int*   cnt         = (int*)(ws + off);  off += 4096;
    int*   tok_of_slot = (int*)(ws + off);  off += (size_t)kE * kCap * 4;
    float* wt_of_slot  = (float*)(ws + off); off += (size_t)kE * kCap * 4;
    u16*   act         = (u16*)(ws + off);  off += (size_t)kE * kCap * kI * 2;   // 64 MB
    size_t off_small = off;
    u16*   xb  = (u16*)(ws + off); off += (size_t)ntok * kH * 2;                 // 8 MB
    u16*   w1t = (u16*)(ws + off); off += (size_t)kE * kH * kI * 2;              // 128 MB
    u16*   w3t = (u16*)(ws + off); off += (size_t)kE * kH * kI * 2;              // 128 MB
    u16*   w2t = (u16*)(ws + off); off += (size_t)kE * kI * kH * 2;              // 128 MB

    hipMemsetAsync(cnt, 0, kE * sizeof(int), stream);
    hipMemsetAsync(d_out, 0, (size_t)out_size * sizeof(float), stream);

    gate_kernel<<<ntok, 256, 0, stream>>>(x, w_gate, gbias, cnt, tok_of_slot, wt_of_slot);

    if (ws_size >= off) {
        // ---- bf16 pre-convert/transpose path ----
        int n8 = ntok * kH / 8;
        prep_x_kernel<<<(n8 + 255) / 256, 256, 0, stream>>>(x, xb, n8);
        {   // w1, w3: [H][I] -> [I][H]
            dim3 g(kI / 64, kH / 64, kE);
            prep_w_kernel<<<g, 256, 0, stream>>>(w1, w1t, kH, kI);
            prep_w_kernel<<<g, 256, 0, stream>>>(w3, w3t, kH, kI);
        }
        {   // w2: [I][H] -> [H][I]
            dim3 g(kH / 64, kI / 64, kE);
            prep_w_kernel<<<g, 256, 0, stream>>>(w2, w2t, kI, kH);
        }
        dim3 g1(kI / 64, kCap / 128, kE);
        gemm1_kernel<<<g1, 256, 0, stream>>>(xb, w1t, w3t, tok_of_slot, cnt, act);
        dim3 g2(kH / 128, kCap / 128, kE);
        gemm2_kernel<<<g2, 256, 0, stream>>>(act, w2t, tok_of_slot, wt_of_slot, cnt, out);
    } else {
        // ---- fallback: fused-conversion path (round-3) ----
        (void)off_small;
        dim3 g1(kI / 64, kCap / 128, kE);
        gemm1_legacy<<<g1, 256, 0, stream>>>(x, w1, w3, tok_of_slot, cnt, act);
        dim3 g2(kH / 128, kCap / 128, kE);
        gemm2_legacy<<<g2, 256, 0, stream>>>(act, w2, tok_of_slot, wt_of_slot, cnt, out);
    }
}

// Round 5
// 732.366 us; speedup vs baseline: 1.1365x; 1.1365x over previous
//
#include <hip/hip_runtime.h>

typedef __attribute__((ext_vector_type(8))) short bf16x8;
typedef __attribute__((ext_vector_type(4))) float f32x4;
typedef unsigned short u16;
typedef unsigned int u32;

constexpr int kH   = 2048;   // hidden
constexpr int kI   = 1024;   // intermediate
constexpr int kE   = 32;     // experts
constexpr int kK   = 8;      // experts per token
constexpr int kG   = 8;      // groups
constexpr int kKG  = 4;      // groups kept
constexpr int kCap = 1024;   // capacity
constexpr float kScale = 2.5f;

__device__ __forceinline__ u16 f2bf(float f) {
    union { float f; u32 u; } v; v.f = f;
    u32 u = v.u + 0x7FFFu + ((v.u >> 16) & 1u);  // RNE
    return (u16)(u >> 16);
}
__device__ __forceinline__ u32 pk2(float a, float b) {
    return (u32)f2bf(a) | ((u32)f2bf(b) << 16);
}
// XOR-swizzled element index for a [row][64] bf16 LDS tile (128 B rows).
__device__ __forceinline__ int swz(int row, int k) {
    return row * 64 + (k ^ ((((row >> 3) ^ row) & 7) << 3));
}
__device__ __forceinline__ int s8(int row) { return ((row >> 3) ^ row) & 7; }

// async global->LDS, 16B per lane; LDS dest must be wave-uniform (HW adds lane*16B)
__device__ __forceinline__ void gload16(const void* g, void* l) {
    __builtin_amdgcn_global_load_lds(
        (const __attribute__((address_space(1))) unsigned int*)g,
        (__attribute__((address_space(3))) unsigned int*)l, 16, 0, 0);
}

// ---------------- gate: sigmoid scores + group-limited top-k routing ----------------
__global__ __launch_bounds__(256) void gate_kernel(
    const float* __restrict__ x, const float* __restrict__ w_gate,
    const float* __restrict__ gbias,
    int* __restrict__ cnt, int* __restrict__ tok_of_slot, float* __restrict__ wt_of_slot)
{
    int tok = blockIdx.x;
    int t = threadIdx.x;
    __shared__ float part[256];
    __shared__ float sc[kE], sb[kE];

    const float* xr = x + (size_t)tok * kH;
    int e = t & 31, c = t >> 5;
    const float* wg = w_gate + e;
    float s = 0.f;
    #pragma unroll 4
    for (int h = c * 256; h < c * 256 + 256; ++h)
        s += xr[h] * wg[(size_t)h * kE];
    part[t] = s;
    __syncthreads();

    if (t < kE) {
        float logit = 0.f;
        #pragma unroll
        for (int cc = 0; cc < 8; ++cc) logit += part[t + 32 * cc];
        float sco = 1.f / (1.f + expf(-logit));
        sc[t] = sco;
        sb[t] = sco + gbias[t];
    }
    __syncthreads();

    if (t == 0) {
        float gsc[kG];
        for (int g = 0; g < kG; ++g) {
            float m1 = -1e30f, m2 = -1e30f;
            for (int j = 0; j < 4; ++j) {
                float v = sb[g * 4 + j];
                if (v > m1) { m2 = m1; m1 = v; } else if (v > m2) { m2 = v; }
            }
            gsc[g] = m1 + m2;
        }
        bool gkeep[kG];
        for (int g = 0; g < kG; ++g) gkeep[g] = false;
        for (int it = 0; it < kKG; ++it) {
            float best = -1e30f; int bi = 0;
            for (int g = 0; g < kG; ++g)
                if (!gkeep[g] && gsc[g] > best) { best = gsc[g]; bi = g; }
            gkeep[bi] = true;
        }
        bool taken[kE];
        for (int i = 0; i < kE; ++i) taken[i] = false;
        int sel[kK]; float selw[kK]; float wsum = 0.f;
        for (int it = 0; it < kK; ++it) {
            float best = -1e30f; int bi = 0;
            for (int i = 0; i < kE; ++i)
                if (gkeep[i >> 2] && !taken[i] && sb[i] > best) { best = sb[i]; bi = i; }
            taken[bi] = true;
            sel[it] = bi; selw[it] = sc[bi]; wsum += sc[bi];
        }
        float scl = kScale / wsum;
        for (int it = 0; it < kK; ++it) {
            int ee = sel[it];
            int slot = atomicAdd(&cnt[ee], 1);
            if (slot < kCap) {
                tok_of_slot[ee * kCap + slot] = tok;
                wt_of_slot[ee * kCap + slot] = selw[it] * scl;
            }
        }
    }
}

// ---------------- prep_x: fp32 -> bf16 streaming convert ----------------
__global__ __launch_bounds__(256) void prep_x_kernel(
    const float* __restrict__ src, u16* __restrict__ dst, int n8)
{
    int i = blockIdx.x * 256 + threadIdx.x;
    if (i >= n8) return;
    const float* p = src + (size_t)i * 8;
    float4 a = *(const float4*)p;
    float4 b = *(const float4*)(p + 4);
    uint4 o;
    o.x = pk2(a.x, a.y); o.y = pk2(a.z, a.w);
    o.z = pk2(b.x, b.y); o.w = pk2(b.z, b.w);
    *(uint4*)(dst + (size_t)i * 8) = o;
}

// ---------------- prep_w: per-expert [R][C] fp32 -> [C][R] bf16 transpose ----------------
__global__ __launch_bounds__(256) void prep_w_kernel(
    const float* __restrict__ src, u16* __restrict__ dst, int R, int C)
{
    __shared__ u16 Tl[64 * 64];
    int e = blockIdx.z;
    int n0 = blockIdx.x * 64;   // C-dim (output row)
    int k0 = blockIdx.y * 64;   // R-dim (output col)
    int t = threadIdx.x;

    const float* se = src + (size_t)e * R * C;
    u16* de = dst + (size_t)e * R * C;

    {
        int bn = (t & 15) * 4, bk = (t >> 4) * 4;
        const float* p = se + (size_t)(k0 + bk) * C + n0 + bn;
        float4 c0 = *(const float4*)p;
        float4 c1 = *(const float4*)(p + C);
        float4 c2 = *(const float4*)(p + 2 * C);
        float4 c3 = *(const float4*)(p + 3 * C);
        uint2 q;
        q.x = pk2(c0.x, c1.x); q.y = pk2(c2.x, c3.x); *(uint2*)&Tl[swz(bn + 0, bk)] = q;
        q.x = pk2(c0.y, c1.y); q.y = pk2(c2.y, c3.y); *(uint2*)&Tl[swz(bn + 1, bk)] = q;
        q.x = pk2(c0.z, c1.z); q.y = pk2(c2.z, c3.z); *(uint2*)&Tl[swz(bn + 2, bk)] = q;
        q.x = pk2(c0.w, c1.w); q.y = pk2(c2.w, c3.w); *(uint2*)&Tl[swz(bn + 3, bk)] = q;
    }
    __syncthreads();
    #pragma unroll
    for (int r = 0; r < 2; ++r) {
        int f = r * 256 + t;
        int n = f >> 3, kk = (f & 7) * 8;
        uint4 v = *(const uint4*)&Tl[swz(n, kk)];
        *(uint4*)(de + (size_t)(n0 + n) * R + k0 + kk) = v;
    }
}

// ---------------- GEMM1: act = silu(xb@w1t^T)*(xb@w3t^T); dbuf + global_load_lds ----------------
__global__ __launch_bounds__(256, 2) void gemm1_kernel(
    const u16* __restrict__ xb, const u16* __restrict__ w1t, const u16* __restrict__ w3t,
    const int* __restrict__ tok_of_slot, const int* __restrict__ cnt,
    u16* __restrict__ act)
{
    int e = blockIdx.z;
    int count = cnt[e];
    int m0 = blockIdx.y * 128;
    if (m0 >= count) return;
    int n0 = blockIdx.x * 64;

    // per buffer: A 8192 | B1 4096 | B3 4096 elems  (2 buffers = 64 KiB total)
    __shared__ u16 sh[2][16384];

    int t = threadIdx.x;

    // A-staging rows are fixed per thread across the K loop: r*32 + (t>>3)
    int tokr[4];
    #pragma unroll
    for (int r = 0; r < 4; ++r) {
        int row = m0 + r * 32 + (t >> 3);
        int tk = (row < count) ? tok_of_slot[e * kCap + row] : 0;
        tokr[r] = (tk >= 0 && tk < 65536) ? tk : 0;   // clamp poison/stale
    }

    const u16* w1e = w1t + (size_t)e * kH * kI;
    const u16* w3e = w3t + (size_t)e * kH * kI;

    int oct = t & 7;
    int wb = (t >> 6) * 512;   // wave chunk-base in elems (64 chunks * 8)

    // stage tile at k0 into buffer b (pre-swizzled global source, linear LDS dest)
    auto stage = [&](int b, int k0) {
        #pragma unroll
        for (int r = 0; r < 4; ++r) {
            int row = r * 32 + (t >> 3);
            const u16* src = xb + (size_t)tokr[r] * kH + k0 + ((oct ^ s8(row)) << 3);
            gload16(src, &sh[b][r * 2048 + wb]);
        }
        #pragma unroll
        for (int r = 0; r < 2; ++r) {
            int n = r * 32 + (t >> 3);
            size_t go = (size_t)(n0 + n) * kH + k0 + ((oct ^ s8(n)) << 3);
            gload16(w1e + go, &sh[b][8192 + r * 2048 + wb]);
            gload16(w3e + go, &sh[b][12288 + r * 2048 + wb]);
        }
    };

    int lane = t & 63;
    int wv = t >> 6;
    int wm = (wv >> 1) * 64;
    int wn = (wv & 1) * 32;
    int lr = lane & 15;
    int kg = lane >> 4;

    f32x4 accg[4][2], accu[4][2];
    #pragma unroll
    for (int i = 0; i < 4; ++i)
        #pragma unroll
        for (int j = 0; j < 2; ++j) {
            accg[i][j] = f32x4{0.f, 0.f, 0.f, 0.f};
            accu[i][j] = f32x4{0.f, 0.f, 0.f, 0.f};
        }

    stage(0, 0);
    __syncthreads();                       // implicit vmcnt(0) drain
    int buf = 0;
    constexpr int NT = kH / 64;
    for (int kt = 0; kt < NT; ++kt) {
        if (kt + 1 < NT) stage(buf ^ 1, (kt + 1) * 64);
        const u16* As  = &sh[buf][0];
        const u16* B1s = &sh[buf][8192];
        const u16* B3s = &sh[buf][12288];
        #pragma unroll
        for (int h = 0; h < 2; ++h) {
            int kk = h * 32 + kg * 8;
            bf16x8 a[4];
            #pragma unroll
            for (int i = 0; i < 4; ++i)
                a[i] = *(const bf16x8*)&As[swz(wm + i * 16 + lr, kk)];
            #pragma unroll
            for (int ni = 0; ni < 2; ++ni) {
                bf16x8 b1 = *(const bf16x8*)&B1s[swz(wn + ni * 16 + lr, kk)];
                bf16x8 b3 = *(const bf16x8*)&B3s[swz(wn + ni * 16 + lr, kk)];
                #pragma unroll
                for (int mi = 0; mi < 4; ++mi) {
                    accg[mi][ni] = __builtin_amdgcn_mfma_f32_16x16x32_bf16(a[mi], b1, accg[mi][ni], 0, 0, 0);
                    accu[mi][ni] = __builtin_amdgcn_mfma_f32_16x16x32_bf16(a[mi], b3, accu[mi][ni], 0, 0, 0);
                }
            }
        }
        __syncthreads();                   // drains staged loads; guards overwrite
        buf ^= 1;
    }

    u16* actp = act + (size_t)e * kCap * kI;
    #pragma unroll
    for (int mi = 0; mi < 4; ++mi)
        #pragma unroll
        for (int ni = 0; ni < 2; ++ni)
            #pragma unroll
            for (int j = 0; j < 4; ++j) {
                int srow = m0 + wm + mi * 16 + kg * 4 + j;
                int icol = n0 + wn + ni * 16 + lr;
                float g = accg[mi][ni][j], u = accu[mi][ni][j];
                float sg = g / (1.f + __expf(-g));
                actp[(size_t)srow * kI + icol] = f2bf(sg * u);
            }
}

// ---------------- GEMM2: y = act @ w2t^T; out[tok] += w*y; dbuf + global_load_lds ----------------
__global__ __launch_bounds__(256, 2) void gemm2_kernel(
    const u16* __restrict__ act, const u16* __restrict__ w2t,
    const int* __restrict__ tok_of_slot, const float* __restrict__ wt_of_slot,
    const int* __restrict__ cnt, float* __restrict__ out)
{
    int e = blockIdx.z;
    int count = cnt[e];
    int m0 = blockIdx.y * 128;
    if (m0 >= count) return;
    int n0 = blockIdx.x * 128;

    // per buffer: A 8192 | B 8192 elems (2 buffers = 64 KiB)
    __shared__ u16 sh[2][16384];

    int t = threadIdx.x;

    const u16* ae  = act + (size_t)e * kCap * kI;
    const u16* w2e = w2t + (size_t)e * kI * kH;

    int oct = t & 7;
    int wb = (t >> 6) * 512;

    auto stage = [&](int b, int k0) {
        #pragma unroll
        for (int r = 0; r < 4; ++r) {
            int row = r * 32 + (t >> 3);
            const u16* src = ae + (size_t)(m0 + row) * kI + k0 + ((oct ^ s8(row)) << 3);
            gload16(src, &sh[b][r * 2048 + wb]);
        }
        #pragma unroll
        for (int r = 0; r < 4; ++r) {
            int n = r * 32 + (t >> 3);
            const u16* src = w2e + (size_t)(n0 + n) * kI + k0 + ((oct ^ s8(n)) << 3);
            gload16(src, &sh[b][8192 + r * 2048 + wb]);
        }
    };

    int lane = t & 63;
    int wv = t >> 6;
    int wm = (wv >> 1) * 64;
    int wn = (wv & 1) * 64;
    int lr = lane & 15;
    int kg = lane >> 4;

    f32x4 acc[4][4];
    #pragma unroll
    for (int i = 0; i < 4; ++i)
        #pragma unroll
        for (int j = 0; j < 4; ++j) acc[i][j] = f32x4{0.f, 0.f, 0.f, 0.f};

    stage(0, 0);
    __syncthreads();
    int buf = 0;
    constexpr int NT = kI / 64;
    for (int kt = 0; kt < NT; ++kt) {
        if (kt + 1 < NT) stage(buf ^ 1, (kt + 1) * 64);
        const u16* As = &sh[buf][0];
        const u16* Bs = &sh[buf][8192];
        #pragma unroll
        for (int h = 0; h < 2; ++h) {
            int kk = h * 32 + kg * 8;
            bf16x8 a[4];
            #pragma unroll
            for (int i = 0; i < 4; ++i)
                a[i] = *(const bf16x8*)&As[swz(wm + i * 16 + lr, kk)];
            #pragma unroll
            for (int ni = 0; ni < 4; ++ni) {
                bf16x8 b = *(const bf16x8*)&Bs[swz(wn + ni * 16 + lr, kk)];
                #pragma unroll
                for (int mi = 0; mi < 4; ++mi)
                    acc[mi][ni] = __builtin_amdgcn_mfma_f32_16x16x32_bf16(a[mi], b, acc[mi][ni], 0, 0, 0);
            }
        }
        __syncthreads();
        buf ^= 1;
    }

    // epilogue: tok/wt read straight from L2 (removed from LDS to fit dbuf in 64 KiB)
    #pragma unroll
    for (int mi = 0; mi < 4; ++mi)
        #pragma unroll
        for (int j = 0; j < 4; ++j) {
            int sr = wm + mi * 16 + kg * 4 + j;
            if (m0 + sr < count) {
                int tk  = tok_of_slot[e * kCap + m0 + sr];
                float w = wt_of_slot[e * kCap + m0 + sr];
                #pragma unroll
                for (int ni = 0; ni < 4; ++ni)
                    atomicAdd(&out[(size_t)tk * kH + n0 + wn + ni * 16 + lr],
                              w * acc[mi][ni][j]);
            }
        }
}

// ================= legacy fp32-staging kernels (fallback if ws too small) =================
__global__ __launch_bounds__(256, 3) void gemm1_legacy(
    const float* __restrict__ x, const float* __restrict__ w1g, const float* __restrict__ w3g,
    const int* __restrict__ tok_of_slot, const int* __restrict__ cnt,
    u16* __restrict__ act)
{
    int e = blockIdx.z;
    int count = cnt[e];
    int m0 = blockIdx.y * 128;
    if (m0 >= count) return;
    int n0 = blockIdx.x * 64;

    __shared__ u16 As[128 * 64];
    __shared__ u16 B1s[64 * 64];
    __shared__ u16 B3s[64 * 64];
    __shared__ int toks[128];

    int t = threadIdx.x;
    if (t < 128) {
        int s = m0 + t;
        toks[t] = (s < count) ? tok_of_slot[e * kCap + s] : -1;
    }
    int lane = t & 63, wv = t >> 6;
    int wm = (wv >> 1) * 64, wn = (wv & 1) * 32;
    int lr = lane & 15, kg = lane >> 4;

    f32x4 accg[4][2], accu[4][2];
    #pragma unroll
    for (int i = 0; i < 4; ++i)
        #pragma unroll
        for (int j = 0; j < 2; ++j) {
            accg[i][j] = f32x4{0.f, 0.f, 0.f, 0.f};
            accu[i][j] = f32x4{0.f, 0.f, 0.f, 0.f};
        }
    const float* w1e = w1g + (size_t)e * kH * kI;
    const float* w3e = w3g + (size_t)e * kH * kI;

    for (int k0 = 0; k0 < kH; k0 += 64) {
        __syncthreads();
        #pragma unroll
        for (int r = 0; r < 4; ++r) {
            int f = r * 256 + t;
            int row = f >> 3, k8 = (f & 7) * 8;
            int tk = toks[row];
            float4 v0 = make_float4(0.f, 0.f, 0.f, 0.f), v1 = v0;
            if (tk >= 0) {
                const float* p = x + (size_t)tk * kH + k0 + k8;
                v0 = *(const float4*)p; v1 = *(const float4*)(p + 4);
            }
            uint4 w;
            w.x = pk2(v0.x, v0.y); w.y = pk2(v0.z, v0.w);
            w.z = pk2(v1.x, v1.y); w.w = pk2(v1.z, v1.w);
            *(uint4*)&As[swz(row, k8)] = w;
        }
        {
            int bn = (t & 15) * 4, bk = (t >> 4) * 4;
            const float* p1 = w1e + (size_t)(k0 + bk) * kI + n0 + bn;
            float4 c0 = *(const float4*)p1, c1 = *(const float4*)(p1 + kI),
                   c2 = *(const float4*)(p1 + 2 * kI), c3 = *(const float4*)(p1 + 3 * kI);
            uint2 q;
            q.x = pk2(c0.x, c1.x); q.y = pk2(c2.x, c3.x); *(uint2*)&B1s[swz(bn + 0, bk)] = q;
            q.x = pk2(c0.y, c1.y); q.y = pk2(c2.y, c3.y); *(uint2*)&B1s[swz(bn + 1, bk)] = q;
            q.x = pk2(c0.z, c1.z); q.y = pk2(c2.z, c3.z); *(uint2*)&B1s[swz(bn + 2, bk)] = q;
            q.x = pk2(c0.w, c1.w); q.y = pk2(c2.w, c3.w); *(uint2*)&B1s[swz(bn + 3, bk)] = q;
            const float* p3 = w3e + (size_t)(k0 + bk) * kI + n0 + bn;
            c0 = *(const float4*)p3; c1 = *(const float4*)(p3 + kI);
            c2 = *(const float4*)(p3 + 2 * kI); c3 = *(const float4*)(p3 + 3 * kI);
            q.x = pk2(c0.x, c1.x); q.y = pk2(c2.x, c3.x); *(uint2*)&B3s[swz(bn + 0, bk)] = q;
            q.x = pk2(c0.y, c1.y); q.y = pk2(c2.y, c3.y); *(uint2*)&B3s[swz(bn + 1, bk)] = q;
            q.x = pk2(c0.z, c1.z); q.y = pk2(c2.z, c3.z); *(uint2*)&B3s[swz(bn + 2, bk)] = q;
            q.x = pk2(c0.w, c1.w); q.y = pk2(c2.w, c3.w); *(uint2*)&B3s[swz(bn + 3, bk)] = q;
        }
        __syncthreads();
        #pragma unroll
        for (int h = 0; h < 2; ++h) {
            int kk = h * 32 + kg * 8;
            bf16x8 a[4];
            #pragma unroll
            for (int i = 0; i < 4; ++i)
                a[i] = *(const bf16x8*)&As[swz(wm + i * 16 + lr, kk)];
            #pragma unroll
            for (int ni = 0; ni < 2; ++ni) {
                bf16x8 b1 = *(const bf16x8*)&B1s[swz(wn + ni * 16 + lr, kk)];
                bf16x8 b3 = *(const bf16x8*)&B3s[swz(wn + ni * 16 + lr, kk)];
                #pragma unroll
                for (int mi = 0; mi < 4; ++mi) {
                    accg[mi][ni] = __builtin_amdgcn_mfma_f32_16x16x32_bf16(a[mi], b1, accg[mi][ni], 0, 0, 0);
                    accu[mi][ni] = __builtin_amdgcn_mfma_f32_16x16x32_bf16(a[mi], b3, accu[mi][ni], 0, 0, 0);
                }
            }
        }
    }
    u16* actp = act + (size_t)e * kCap * kI;
    #pragma unroll
    for (int mi = 0; mi < 4; ++mi)
        #pragma unroll
        for (int ni = 0; ni < 2; ++ni)
            #pragma unroll
            for (int j = 0; j < 4; ++j) {
                int srow = m0 + wm + mi * 16 + kg * 4 + j;
                int icol = n0 + wn + ni * 16 + lr;
                float g = accg[mi][ni][j], u = accu[mi][ni][j];
                float sg = g / (1.f + __expf(-g));
                actp[(size_t)srow * kI + icol] = f2bf(sg * u);
            }
}

__global__ __launch_bounds__(256, 3) void gemm2_legacy(
    const u16* __restrict__ act, const float* __restrict__ w2g,
    const int* __restrict__ tok_of_slot, const float* __restrict__ wt_of_slot,
    const int* __restrict__ cnt, float* __restrict__ out)
{
    int e = blockIdx.z;
    int count = cnt[e];
    int m0 = blockIdx.y * 128;
    if (m0 >= count) return;
    int n0 = blockIdx.x * 128;

    __shared__ u16 As[128 * 64];
    __shared__ u16 Bs[128 * 64];
    __shared__ int toks[128];
    __shared__ float wts[128];

    int t = threadIdx.x;
    if (t < 128) {
        int s = m0 + t;
        toks[t] = (s < count) ? tok_of_slot[e * kCap + s] : 0;
        wts[t]  = (s < count) ? wt_of_slot[e * kCap + s] : 0.f;
    }
    int lane = t & 63, wv = t >> 6;
    int wm = (wv >> 1) * 64, wn = (wv & 1) * 64;
    int lr = lane & 15, kg = lane >> 4;

    f32x4 acc[4][4];
    #pragma unroll
    for (int i = 0; i < 4; ++i)
        #pragma unroll
        for (int j = 0; j < 4; ++j) acc[i][j] = f32x4{0.f, 0.f, 0.f, 0.f};

    const u16* ae = act + (size_t)e * kCap * kI;
    const float* w2e = w2g + (size_t)e * kI * kH;

    for (int k0 = 0; k0 < kI; k0 += 64) {
        __syncthreads();
        #pragma unroll
        for (int r = 0; r < 4; ++r) {
            int f = r * 256 + t;
            int row = f >> 3, k8 = (f & 7) * 8;
            uint4 v = *(const uint4*)(ae + (size_t)(m0 + row) * kI + k0 + k8);
            *(uint4*)&As[swz(row, k8)] = v;
        }
        #pragma unroll
        for (int r = 0; r < 2; ++r) {
            int f = r * 256 + t;
            int bn = (f & 31) * 4, bk = (f >> 5) * 4;
            const float* p = w2e + (size_t)(k0 + bk) * kH + n0 + bn;
            float4 c0 = *(const float4*)p, c1 = *(const float4*)(p + kH),
                   c2 = *(const float4*)(p + 2 * kH), c3 = *(const float4*)(p + 3 * kH);
            uint2 q;
            q.x = pk2(c0.x, c1.x); q.y = pk2(c2.x, c3.x); *(uint2*)&Bs[swz(bn + 0, bk)] = q;
            q.x = pk2(c0.y, c1.y); q.y = pk2(c2.y, c3.y); *(uint2*)&Bs[swz(bn + 1, bk)] = q;
            q.x = pk2(c0.z, c1.z); q.y = pk2(c2.z, c3.z); *(uint2*)&Bs[swz(bn + 2, bk)] = q;
            q.x = pk2(c0.w, c1.w); q.y = pk2(c2.w, c3.w); *(uint2*)&Bs[swz(bn + 3, bk)] = q;
        }
        __syncthreads();
        #pragma unroll
        for (int h = 0; h < 2; ++h) {
            int kk = h * 32 + kg * 8;
            bf16x8 a[4];
            #pragma unroll
            for (int i = 0; i < 4; ++i)
                a[i] = *(const bf16x8*)&As[swz(wm + i * 16 + lr, kk)];
            #pragma unroll
            for (int ni = 0; ni < 4; ++ni) {
                bf16x8 b = *(const bf16x8*)&Bs[swz(wn + ni * 16 + lr, kk)];
                #pragma unroll
                for (int mi = 0; mi < 4; ++mi)
                    acc[mi][ni] = __builtin_amdgcn_mfma_f32_16x16x32_bf16(a[mi], b, acc[mi][ni], 0, 0, 0);
            }
        }
    }
    #pragma unroll
    for (int mi = 0; mi < 4; ++mi)
        #pragma unroll
        for (int ni = 0; ni < 4; ++ni)
            #pragma unroll
            for (int j = 0; j < 4; ++j) {
                int sr = wm + mi * 16 + kg * 4 + j;
                if (m0 + sr < count) {
                    atomicAdd(&out[(size_t)toks[sr] * kH + n0 + wn + ni * 16 + lr],
                              wts[sr] * acc[mi][ni][j]);
                }
            }
}

extern "C" void kernel_launch(void* const* d_in, const int* in_sizes, int n_in,
                              void* d_out, int out_size, void* d_ws, size_t ws_size,
                              hipStream_t stream) {
    const float* x      = (const float*)d_in[0];
    const float* w_gate = (const float*)d_in[1];
    const float* gbias  = (const float*)d_in[2];
    const float* w1     = (const float*)d_in[3];
    const float* w3     = (const float*)d_in[4];
    const float* w2     = (const float*)d_in[5];
    float* out = (float*)d_out;

    int ntok = in_sizes[0] / kH;

    char* ws = (char*)d_ws;
    size_t off = 0;
    int*   cnt         = (int*)(ws + off);  off += 4096;
    int*   tok_of_slot = (int*)(ws + off);  off += (size_t)kE * kCap * 4;
    float* wt_of_slot  = (float*)(ws + off); off += (size_t)kE * kCap * 4;
    u16*   act         = (u16*)(ws + off);  off += (size_t)kE * kCap * kI * 2;   // 64 MB
    u16*   xb  = (u16*)(ws + off); off += (size_t)ntok * kH * 2;                 // 8 MB
    u16*   w1t = (u16*)(ws + off); off += (size_t)kE * kH * kI * 2;              // 128 MB
    u16*   w3t = (u16*)(ws + off); off += (size_t)kE * kH * kI * 2;              // 128 MB
    u16*   w2t = (u16*)(ws + off); off += (size_t)kE * kI * kH * 2;              // 128 MB

    hipMemsetAsync(cnt, 0, kE * sizeof(int), stream);
    hipMemsetAsync(d_out, 0, (size_t)out_size * sizeof(float), stream);

    gate_kernel<<<ntok, 256, 0, stream>>>(x, w_gate, gbias, cnt, tok_of_slot, wt_of_slot);

    if (ws_size >= off) {
        int n8 = ntok * kH / 8;
        prep_x_kernel<<<(n8 + 255) / 256, 256, 0, stream>>>(x, xb, n8);
        {
            dim3 g(kI / 64, kH / 64, kE);
            prep_w_kernel<<<g, 256, 0, stream>>>(w1, w1t, kH, kI);
            prep_w_kernel<<<g, 256, 0, stream>>>(w3, w3t, kH, kI);
        }
        {
            dim3 g(kH / 64, kI / 64, kE);
            prep_w_kernel<<<g, 256, 0, stream>>>(w2, w2t, kI, kH);
        }
        dim3 g1(kI / 64, kCap / 128, kE);
        gemm1_kernel<<<g1, 256, 0, stream>>>(xb, w1t, w3t, tok_of_slot, cnt, act);
        dim3 g2(kH / 128, kCap / 128, kE);
        gemm2_kernel<<<g2, 256, 0, stream>>>(act, w2t, tok_of_slot, wt_of_slot, cnt, out);
    } else {
        dim3 g1(kI / 64, kCap / 128, kE);
        gemm1_legacy<<<g1, 256, 0, stream>>>(x, w1, w3, tok_of_slot, cnt, act);
        dim3 g2(kH / 128, kCap / 128, kE);
        gemm2_legacy<<<g2, 256, 0, stream>>>(act, w2, tok_of_slot, wt_of_slot, cnt, out);
    }
}